// Round 1
// baseline (1289.189 us; speedup 1.0000x reference)
//
#include <hip/hip_runtime.h>

typedef unsigned short u16;
typedef __attribute__((ext_vector_type(8))) short bf16x8;
typedef __attribute__((ext_vector_type(4))) float f32x4;

#define MFMA16x16(a, b, c) __builtin_amdgcn_mfma_f32_16x16x32_bf16((a), (b), (c), 0, 0, 0)

#define N_B 128
#define N_K 32
#define N_I 12000
#define N_H 600
#define N_HP 640
#define N_LAT 200
#define N_DP 224
#define N_2LAT 400
#define N_ROWS 4096
#define EPSF 1e-12f

// out layout (floats): z[4096*200] | new_output[128*12000] | kl[1] | x[4096*12000]
#define OFF_NO 819200
#define OFF_KL 2355200
#define OFF_X  2355201

__device__ __forceinline__ u16 f2bf(float f) {
    unsigned u = __builtin_bit_cast(unsigned, f);
    return (u16)((u + 0x7fffu + ((u >> 16) & 1u)) >> 16);
}

// ---------------- W1 [12000][600] f32 -> W1T bf16 [640][12000] (pad n with 0)
__global__ __launch_bounds__(256) void k_w1t(const float* __restrict__ W1, u16* __restrict__ w1t) {
    __shared__ float tile[32][33];
    const int k0 = blockIdx.x * 32, n0 = blockIdx.y * 32;
    const int x = threadIdx.x, y = threadIdx.y;
#pragma unroll
    for (int r = 0; r < 4; r++) {
        int kk = y * 4 + r;
        int n = n0 + x;
        tile[kk][x] = (n < N_H) ? W1[(size_t)(k0 + kk) * N_H + n] : 0.f;
    }
    __syncthreads();
#pragma unroll
    for (int r = 0; r < 4; r++) {
        int nl = y * 4 + r;
        w1t[(size_t)(n0 + nl) * N_I + k0 + x] = f2bf(tile[x][nl]);
    }
}

// ---------------- W2 [600][400] f32 -> W2T bf16 [400][640] (pad k with 0)
__global__ __launch_bounds__(256) void k_w2t(const float* __restrict__ W2, u16* __restrict__ w2t) {
    __shared__ float tile[32][33];
    const int k0 = blockIdx.x * 32, n0 = blockIdx.y * 32;
    const int x = threadIdx.x, y = threadIdx.y;
#pragma unroll
    for (int r = 0; r < 4; r++) {
        int kk = y * 4 + r;
        int n = n0 + x;
        tile[kk][x] = ((k0 + kk) < N_H && n < N_2LAT) ? W2[(size_t)(k0 + kk) * N_2LAT + n] : 0.f;
    }
    __syncthreads();
#pragma unroll
    for (int r = 0; r < 4; r++) {
        int nl = y * 4 + r;
        if (n0 + nl < N_2LAT)
            w2t[(size_t)(n0 + nl) * N_HP + k0 + x] = f2bf(tile[x][nl]);
    }
}

// ---------------- items [12000][200] -> l2norm -> bf16 [12000][224] (pad 0)
__global__ __launch_bounds__(256) void k_itemn(const float* __restrict__ items, u16* __restrict__ itn) {
    const int r = blockIdx.x * 4 + (threadIdx.x >> 6);
    const int lane = threadIdx.x & 63;
    const float4* src = (const float4*)(items + (size_t)r * N_LAT);
    float4 v = make_float4(0.f, 0.f, 0.f, 0.f);
    if (lane < 50) v = src[lane];
    float sq = v.x * v.x + v.y * v.y + v.z * v.z + v.w * v.w;
#pragma unroll
    for (int m = 1; m < 64; m <<= 1) sq += __shfl_xor(sq, m);
    const float inv = 1.f / fmaxf(sqrtf(sq), EPSF);
    u16* dst = itn + (size_t)r * N_DP;
    if (lane < 50) {
        ushort4 pk;
        pk.x = f2bf(v.x * inv); pk.y = f2bf(v.y * inv);
        pk.z = f2bf(v.z * inv); pk.w = f2bf(v.w * inv);
        *(ushort4*)(dst + lane * 4) = pk;
    } else if (lane < 56) {
        ushort4 pk; pk.x = 0; pk.y = 0; pk.z = 0; pk.w = 0;
        *(ushort4*)(dst + lane * 4) = pk;
    }
}

// ---------------- x rows: gather gram[idx], mask by rating>0, l1 then l2 normalize
__global__ __launch_bounds__(256) void k_xnorm(const float* __restrict__ rating, const int* __restrict__ idx,
                                               const float* __restrict__ gram, float* __restrict__ x_out,
                                               u16* __restrict__ xb) {
    const int row = blockIdx.x;
    const int b = row >> 5;
    const int gi = idx[row];
    const float4* grow = (const float4*)(gram + (size_t)gi * N_I);
    const float4* urow = (const float4*)(rating + (size_t)b * N_I);
    float sa = 0.f, sq = 0.f;
    for (int i = threadIdx.x; i < N_I / 4; i += 256) {
        float4 g = grow[i], u = urow[i];
        float m0 = u.x > 0.f ? g.x : 0.f;
        float m1 = u.y > 0.f ? g.y : 0.f;
        float m2 = u.z > 0.f ? g.z : 0.f;
        float m3 = u.w > 0.f ? g.w : 0.f;
        sa += fabsf(m0) + fabsf(m1) + fabsf(m2) + fabsf(m3);
        sq += m0 * m0 + m1 * m1 + m2 * m2 + m3 * m3;
    }
    __shared__ float red[8];
#pragma unroll
    for (int m = 1; m < 64; m <<= 1) { sa += __shfl_xor(sa, m); sq += __shfl_xor(sq, m); }
    const int w = threadIdx.x >> 6;
    if ((threadIdx.x & 63) == 0) { red[w] = sa; red[4 + w] = sq; }
    __syncthreads();
    sa = red[0] + red[1] + red[2] + red[3];
    sq = red[4] + red[5] + red[6] + red[7];
    const float s1 = fmaxf(sa, EPSF);
    const float s2 = fmaxf(sqrtf(sq) / s1, EPSF);
    const float scale = 1.f / (s1 * s2);
    float* xo = x_out + (size_t)row * N_I;      // odd float offset -> scalar stores
    u16* xbo = xb + (size_t)row * N_I;
    for (int i = threadIdx.x; i < N_I / 4; i += 256) {
        float4 g = grow[i], u = urow[i];
        float m0 = (u.x > 0.f ? g.x : 0.f) * scale;
        float m1 = (u.y > 0.f ? g.y : 0.f) * scale;
        float m2 = (u.z > 0.f ? g.z : 0.f) * scale;
        float m3 = (u.w > 0.f ? g.w : 0.f) * scale;
        xo[i * 4 + 0] = m0; xo[i * 4 + 1] = m1; xo[i * 4 + 2] = m2; xo[i * 4 + 3] = m3;
        ushort4 pk;
        pk.x = f2bf(m0); pk.y = f2bf(m1); pk.z = f2bf(m2); pk.w = f2bf(m3);
        *(ushort4*)(xbo + i * 4) = pk;
    }
}

// ---------------- GEMM1: h = tanh(x @ W1 + b1), bf16 MFMA, 128x128 tile, BK=32
__global__ __launch_bounds__(256) void k_gemm1(const u16* __restrict__ xb, const u16* __restrict__ w1t,
                                               const float* __restrict__ b1, u16* __restrict__ hbuf) {
    __shared__ u16 Als[128 * 40];   // rows padded to 40 shorts (80B, 16B-aligned, 2-way banks = free)
    __shared__ u16 Bls[128 * 40];
    const int m0 = blockIdx.x * 128;
    const int n0 = blockIdx.y * 128;
    const int t = threadIdx.x;
    const int lane = t & 63, w = t >> 6;
    const int wr = (w >> 1) * 64, wc = (w & 1) * 64;
    const int q = lane >> 4, l15 = lane & 15;

    const int rA0 = t >> 2, cA = t & 3;
    const int rA1 = rA0 + 64;
    const size_t xg0 = (size_t)(m0 + rA0) * N_I + cA * 8;
    const size_t xg1 = (size_t)(m0 + rA1) * N_I + cA * 8;
    const size_t wg0 = (size_t)(n0 + rA0) * N_I + cA * 8;
    const size_t wg1 = (size_t)(n0 + rA1) * N_I + cA * 8;
    const int ls0 = rA0 * 40 + cA * 8;
    const int ls1 = rA1 * 40 + cA * 8;

    f32x4 acc[4][4];
#pragma unroll
    for (int i = 0; i < 4; i++)
#pragma unroll
        for (int j = 0; j < 4; j++) acc[i][j] = (f32x4){0.f, 0.f, 0.f, 0.f};

    for (int k0 = 0; k0 < N_I; k0 += 32) {
        uint4 a0 = *(const uint4*)(xb + xg0 + k0);
        uint4 a1 = *(const uint4*)(xb + xg1 + k0);
        uint4 g0 = *(const uint4*)(w1t + wg0 + k0);
        uint4 g1 = *(const uint4*)(w1t + wg1 + k0);
        __syncthreads();
        *(uint4*)(Als + ls0) = a0;
        *(uint4*)(Als + ls1) = a1;
        *(uint4*)(Bls + ls0) = g0;
        *(uint4*)(Bls + ls1) = g1;
        __syncthreads();
        bf16x8 af[4], bf[4];
#pragma unroll
        for (int f = 0; f < 4; f++) af[f] = *(const bf16x8*)(Als + (wr + f * 16 + l15) * 40 + q * 8);
#pragma unroll
        for (int f = 0; f < 4; f++) bf[f] = *(const bf16x8*)(Bls + (wc + f * 16 + l15) * 40 + q * 8);
#pragma unroll
        for (int fm = 0; fm < 4; fm++)
#pragma unroll
            for (int fn = 0; fn < 4; fn++)
                acc[fm][fn] = MFMA16x16(af[fm], bf[fn], acc[fm][fn]);
    }
#pragma unroll
    for (int fm = 0; fm < 4; fm++) {
        const int rowb = m0 + wr + fm * 16 + q * 4;
#pragma unroll
        for (int fn = 0; fn < 4; fn++) {
            const int col = n0 + wc + fn * 16 + l15;
            const float bias = (col < N_H) ? b1[col] : 0.f;
#pragma unroll
            for (int r = 0; r < 4; r++) {
                float e = acc[fm][fn][r] + bias;
                hbuf[(size_t)(rowb + r) * N_HP + col] = f2bf(tanhf(e));
            }
        }
    }
}

// ---------------- GEMM2: enc = h @ W2 + b2 ; z, zn, KL epilogue. 1 wave per 16 rows.
__global__ __launch_bounds__(64) void k_gemm2(const u16* __restrict__ hbuf, const u16* __restrict__ w2t,
                                              const float* __restrict__ b2, float* __restrict__ z_out,
                                              float* __restrict__ kl_out, u16* __restrict__ znb) {
    const int m0 = blockIdx.x * 16;
    const int lane = threadIdx.x;
    const int q = lane >> 4, l15 = lane & 15;
    f32x4 acc[25];
#pragma unroll
    for (int f = 0; f < 25; f++) acc[f] = (f32x4){0.f, 0.f, 0.f, 0.f};
    for (int s = 0; s < N_HP / 32; s++) {
        bf16x8 a = *(const bf16x8*)(hbuf + (size_t)(m0 + l15) * N_HP + s * 32 + q * 8);
#pragma unroll
        for (int f = 0; f < 25; f++) {
            bf16x8 bb = *(const bf16x8*)(w2t + (size_t)(f * 16 + l15) * N_HP + s * 32 + q * 8);
            acc[f] = MFMA16x16(a, bb, acc[f]);
        }
    }
    float sumsq[4] = {0.f, 0.f, 0.f, 0.f}, kls[4] = {0.f, 0.f, 0.f, 0.f};
#pragma unroll
    for (int f = 0; f < 25; f++) {
        const int n = f * 16 + l15;
        const float bias = b2[n];
#pragma unroll
        for (int r = 0; r < 4; r++) {
            float e = acc[f][r] + bias;
            if (n < N_LAT) {
                sumsq[r] += e * e;
                kls[r] += e * e;
                z_out[(size_t)(m0 + q * 4 + r) * N_LAT + n] = e;
            } else {
                kls[r] += __expf(e) - 1.f - e;
            }
        }
    }
#pragma unroll
    for (int r = 0; r < 4; r++)
#pragma unroll
        for (int m = 1; m < 16; m <<= 1) {
            sumsq[r] += __shfl_xor(sumsq[r], m);
            kls[r] += __shfl_xor(kls[r], m);
        }
    float inv[4];
#pragma unroll
    for (int r = 0; r < 4; r++) inv[r] = 1.f / fmaxf(sqrtf(sumsq[r]), EPSF);
#pragma unroll
    for (int f = 0; f < 25; f++) {
        const int n = f * 16 + l15;
        const float bias = b2[n];
#pragma unroll
        for (int r = 0; r < 4; r++) {
            const int row = m0 + q * 4 + r;
            float e = acc[f][r] + bias;
            if (n < N_LAT) znb[(size_t)row * N_DP + n] = f2bf(e * inv[r]);
            else if (n < N_DP) znb[(size_t)row * N_DP + n] = 0;
        }
    }
    if (l15 == 0) {
        float s = (kls[0] + kls[1] + kls[2] + kls[3]) * (0.5f / (float)N_ROWS);
        atomicAdd(kl_out, s);
    }
}

// ---------------- GEMM3 fused: new_output[b][i] = log(mean_k exp(zn[b,k]·itn[i]*10) + 1)
__global__ __launch_bounds__(256) void k_outred(const u16* __restrict__ znb, const u16* __restrict__ itn,
                                                float* __restrict__ no_out) {
    __shared__ u16 zls[32 * N_DP];
    const int b = blockIdx.x;
    const int t = threadIdx.x;
    for (int i = t; i < (32 * N_DP) / 8; i += 256)
        ((uint4*)zls)[i] = ((const uint4*)(znb + (size_t)b * 32 * N_DP))[i];
    __syncthreads();
    const int lane = t & 63, w = t >> 6;
    const int q = lane >> 4, l15 = lane & 15;
    bf16x8 af[2][7];
#pragma unroll
    for (int hh = 0; hh < 2; hh++)
#pragma unroll
        for (int s = 0; s < 7; s++)
            af[hh][s] = *(const bf16x8*)(zls + (hh * 16 + l15) * N_DP + s * 32 + q * 8);
    for (int tt = blockIdx.y * 4 + w; tt < 750; tt += 128) {
        const int i0 = tt * 16;
        bf16x8 bfr[7];
#pragma unroll
        for (int s = 0; s < 7; s++)
            bfr[s] = *(const bf16x8*)(itn + (size_t)(i0 + l15) * N_DP + s * 32 + q * 8);
        f32x4 a0 = (f32x4){0.f, 0.f, 0.f, 0.f}, a1 = (f32x4){0.f, 0.f, 0.f, 0.f};
#pragma unroll
        for (int s = 0; s < 7; s++) {
            a0 = MFMA16x16(af[0][s], bfr[s], a0);
            a1 = MFMA16x16(af[1][s], bfr[s], a1);
        }
        float se = 0.f;
#pragma unroll
        for (int r = 0; r < 4; r++) se += __expf(a0[r] * 10.f) + __expf(a1[r] * 10.f);
        se += __shfl_xor(se, 16);
        se += __shfl_xor(se, 32);
        if (lane < 16)
            no_out[(size_t)b * N_I + i0 + lane] = __logf(se * (1.f / 32.f) + 1.f);
    }
}

extern "C" void kernel_launch(void* const* d_in, const int* in_sizes, int n_in,
                              void* d_out, int out_size, void* d_ws, size_t ws_size,
                              hipStream_t stream) {
    const float* rating = (const float*)d_in[0];
    const int* idx = (const int*)d_in[1];
    const float* gram = (const float*)d_in[2];
    const float* W1 = (const float*)d_in[3];
    const float* b1 = (const float*)d_in[4];
    const float* W2 = (const float*)d_in[5];
    const float* b2 = (const float*)d_in[6];
    const float* items = (const float*)d_in[7];

    float* out = (float*)d_out;
    float* z_out = out;
    float* no_out = out + OFF_NO;
    float* kl_out = out + OFF_KL;
    float* x_out = out + OFF_X;

    char* ws = (char*)d_ws;
    u16* xb   = (u16*)(ws);                  // 4096*12000*2 = 98,304,000
    u16* w1t  = (u16*)(ws + 98304000);       // 640*12000*2  = 15,360,000
    u16* w2t  = (u16*)(ws + 113664000);      // 400*640*2    =    512,000
    u16* hbuf = (u16*)(ws + 114176000);      // 4096*640*2   =  5,242,880
    u16* znb  = (u16*)(ws + 119418880);      // 4096*224*2   =  1,835,008
    u16* itn  = (u16*)(ws + 121253888);      // 12000*224*2  =  5,376,000  (total ~126.6 MB)

    hipMemsetAsync(kl_out, 0, 4, stream);
    k_w1t<<<dim3(N_I / 32, N_HP / 32), dim3(32, 8), 0, stream>>>(W1, w1t);
    k_w2t<<<dim3(N_HP / 32, 13), dim3(32, 8), 0, stream>>>(W2, w2t);
    k_itemn<<<N_I / 4, 256, 0, stream>>>(items, itn);
    k_xnorm<<<N_ROWS, 256, 0, stream>>>(rating, idx, gram, x_out, xb);
    k_gemm1<<<dim3(N_ROWS / 128, N_HP / 128), 256, 0, stream>>>(xb, w1t, b1, hbuf);
    k_gemm2<<<N_ROWS / 16, 64, 0, stream>>>(hbuf, w2t, b2, z_out, kl_out, znb);
    k_outred<<<dim3(N_B, 32), 256, 0, stream>>>(znb, itn, no_out);
}

// Round 2
// 1080.178 us; speedup vs baseline: 1.1935x; 1.1935x over previous
//
#include <hip/hip_runtime.h>

typedef unsigned short u16;
typedef __attribute__((ext_vector_type(8))) short bf16x8;
typedef __attribute__((ext_vector_type(4))) float f32x4;

#define MFMA16x16(a, b, c) __builtin_amdgcn_mfma_f32_16x16x32_bf16((a), (b), (c), 0, 0, 0)

#define N_B 128
#define N_K 32
#define N_I 12000
#define N_H 600
#define N_HP 640
#define N_LAT 200
#define N_DP 224
#define N_2LAT 400
#define N_ROWS 4096
#define EPSF 1e-12f
#define SPLITK 5
#define KC 2400

// out layout (floats): z[4096*200] | new_output[128*12000] | kl[1] | x[4096*12000]
#define OFF_NO 819200
#define OFF_KL 2355200
#define OFF_X  2355201

__device__ __forceinline__ u16 f2bf(float f) {
    unsigned u = __builtin_bit_cast(unsigned, f);
    return (u16)((u + 0x7fffu + ((u >> 16) & 1u)) >> 16);
}

// async 16B/lane global->LDS DMA; LDS dest = uniform base + lane*16
__device__ __forceinline__ void async_ld16(const u16* g, u16* l) {
    __builtin_amdgcn_global_load_lds(
        (const __attribute__((address_space(1))) unsigned int*)g,
        (__attribute__((address_space(3))) unsigned int*)l, 16, 0, 0);
}

// ---------------- W1 [12000][600] f32 -> W1T bf16 [640][12000] (pad n with 0)
__global__ __launch_bounds__(256) void k_w1t(const float* __restrict__ W1, u16* __restrict__ w1t) {
    __shared__ float tile[32][33];
    const int k0 = blockIdx.x * 32, n0 = blockIdx.y * 32;
    const int x = threadIdx.x, y = threadIdx.y;
#pragma unroll
    for (int r = 0; r < 4; r++) {
        int kk = y * 4 + r;
        int n = n0 + x;
        tile[kk][x] = (n < N_H) ? W1[(size_t)(k0 + kk) * N_H + n] : 0.f;
    }
    __syncthreads();
#pragma unroll
    for (int r = 0; r < 4; r++) {
        int nl = y * 4 + r;
        w1t[(size_t)(n0 + nl) * N_I + k0 + x] = f2bf(tile[x][nl]);
    }
}

// ---------------- W2 [600][400] f32 -> W2T bf16 [400][640] (pad k with 0)
__global__ __launch_bounds__(256) void k_w2t(const float* __restrict__ W2, u16* __restrict__ w2t) {
    __shared__ float tile[32][33];
    const int k0 = blockIdx.x * 32, n0 = blockIdx.y * 32;
    const int x = threadIdx.x, y = threadIdx.y;
#pragma unroll
    for (int r = 0; r < 4; r++) {
        int kk = y * 4 + r;
        int n = n0 + x;
        tile[kk][x] = ((k0 + kk) < N_H && n < N_2LAT) ? W2[(size_t)(k0 + kk) * N_2LAT + n] : 0.f;
    }
    __syncthreads();
#pragma unroll
    for (int r = 0; r < 4; r++) {
        int nl = y * 4 + r;
        if (n0 + nl < N_2LAT)
            w2t[(size_t)(n0 + nl) * N_HP + k0 + x] = f2bf(tile[x][nl]);
    }
}

// ---------------- items [12000][200] -> l2norm -> bf16 [12000][224] (pad 0)
__global__ __launch_bounds__(256) void k_itemn(const float* __restrict__ items, u16* __restrict__ itn) {
    const int r = blockIdx.x * 4 + (threadIdx.x >> 6);
    const int lane = threadIdx.x & 63;
    const float4* src = (const float4*)(items + (size_t)r * N_LAT);
    float4 v = make_float4(0.f, 0.f, 0.f, 0.f);
    if (lane < 50) v = src[lane];
    float sq = v.x * v.x + v.y * v.y + v.z * v.z + v.w * v.w;
#pragma unroll
    for (int m = 1; m < 64; m <<= 1) sq += __shfl_xor(sq, m);
    const float inv = 1.f / fmaxf(sqrtf(sq), EPSF);
    u16* dst = itn + (size_t)r * N_DP;
    if (lane < 50) {
        ushort4 pk;
        pk.x = f2bf(v.x * inv); pk.y = f2bf(v.y * inv);
        pk.z = f2bf(v.z * inv); pk.w = f2bf(v.w * inv);
        *(ushort4*)(dst + lane * 4) = pk;
    } else if (lane < 56) {
        ushort4 pk; pk.x = 0; pk.y = 0; pk.z = 0; pk.w = 0;
        *(ushort4*)(dst + lane * 4) = pk;
    }
}

// ---------------- x rows: gather gram[idx], mask by rating>0, l1+l2 normalize. Single pass:
// masked values cached in 12 float4 regs, so gram row is read once.
__global__ __launch_bounds__(256) void k_xnorm(const float* __restrict__ rating, const int* __restrict__ idx,
                                               const float* __restrict__ gram, float* __restrict__ x_out,
                                               u16* __restrict__ xb) {
    const int row = blockIdx.x;
    const int b = row >> 5;
    const int gi = idx[row];
    const float4* grow = (const float4*)(gram + (size_t)gi * N_I);
    const float4* urow = (const float4*)(rating + (size_t)b * N_I);
    float4 mv[12];
    float sa = 0.f, sq = 0.f;
#pragma unroll
    for (int j = 0; j < 12; j++) {
        int i = threadIdx.x + j * 256;
        if (i < N_I / 4) {
            float4 g = grow[i], u = urow[i];
            float4 m;
            m.x = u.x > 0.f ? g.x : 0.f;
            m.y = u.y > 0.f ? g.y : 0.f;
            m.z = u.z > 0.f ? g.z : 0.f;
            m.w = u.w > 0.f ? g.w : 0.f;
            mv[j] = m;
            sa += fabsf(m.x) + fabsf(m.y) + fabsf(m.z) + fabsf(m.w);
            sq += m.x * m.x + m.y * m.y + m.z * m.z + m.w * m.w;
        }
    }
    __shared__ float red[8];
#pragma unroll
    for (int m = 1; m < 64; m <<= 1) { sa += __shfl_xor(sa, m); sq += __shfl_xor(sq, m); }
    const int w = threadIdx.x >> 6;
    if ((threadIdx.x & 63) == 0) { red[w] = sa; red[4 + w] = sq; }
    __syncthreads();
    sa = red[0] + red[1] + red[2] + red[3];
    sq = red[4] + red[5] + red[6] + red[7];
    const float s1 = fmaxf(sa, EPSF);
    const float s2 = fmaxf(sqrtf(sq) / s1, EPSF);
    const float scale = 1.f / (s1 * s2);
    float* xo = x_out + (size_t)row * N_I;      // odd float offset -> scalar dword stores (L2 merges)
    u16* xbo = xb + (size_t)row * N_I;
#pragma unroll
    for (int j = 0; j < 12; j++) {
        int i = threadIdx.x + j * 256;
        if (i < N_I / 4) {
            float4 m = mv[j];
            float m0 = m.x * scale, m1 = m.y * scale, m2 = m.z * scale, m3 = m.w * scale;
            xo[i * 4 + 0] = m0; xo[i * 4 + 1] = m1; xo[i * 4 + 2] = m2; xo[i * 4 + 3] = m3;
            ushort4 pk;
            pk.x = f2bf(m0); pk.y = f2bf(m1); pk.z = f2bf(m2); pk.w = f2bf(m3);
            *(ushort4*)(xbo + i * 4) = pk;
        }
    }
}

// ---------------- GEMM1 split-K: accbuf += x_chunk @ W1_chunk. 128x128 tile, BK=32, K=2400/block.
// LDS chunk-major: slot(row,kchunk) = (row>>4)*64 + kchunk*16 + (row&15); 16B slots.
// global_load_lds lands lane l at slot base+l (l = kchunk*16 + row15), frag reads are
// consecutive-lane-consecutive-slot => 2-way bank alias only (free).
__global__ __launch_bounds__(256) void k_gemm1(const u16* __restrict__ xb, const u16* __restrict__ w1t,
                                               float* __restrict__ accbuf) {
    __shared__ u16 Als[128 * 32];
    __shared__ u16 Bls[128 * 32];
    const int m0 = blockIdx.x * 128;
    const int n0 = blockIdx.y * 128;
    const int kbase = blockIdx.z * KC;
    const int t = threadIdx.x;
    const int lane = t & 63, w = t >> 6;
    const int wr = (w >> 1) * 64, wc = (w & 1) * 64;
    const int q = lane >> 4, l15 = lane & 15;

    // staging: wave w DMAs groups 2w, 2w+1 (16 rows each) for A and B
    const int r0 = (2 * w) * 16 + l15;          // tile-local row, group 2w
    const int c0 = q * 8;                       // k-chunk offset (shorts)
    const u16* gA0 = xb + (size_t)(m0 + r0) * N_I + kbase + c0;
    const u16* gA1 = gA0 + (size_t)16 * N_I;
    const u16* gB0 = w1t + (size_t)(n0 + r0) * N_I + kbase + c0;
    const u16* gB1 = gB0 + (size_t)16 * N_I;
    u16* lA0 = Als + (2 * w) * 512;             // group = 64 slots * 8 shorts
    u16* lA1 = Als + (2 * w + 1) * 512;
    u16* lB0 = Bls + (2 * w) * 512;
    u16* lB1 = Bls + (2 * w + 1) * 512;

    f32x4 acc[4][4];
#pragma unroll
    for (int i = 0; i < 4; i++)
#pragma unroll
        for (int j = 0; j < 4; j++) acc[i][j] = (f32x4){0.f, 0.f, 0.f, 0.f};

    for (int ks = 0; ks < KC / 32; ks++) {
        const int koff = ks * 32;
        __syncthreads();                         // previous iter's frags consumed
        async_ld16(gA0 + koff, lA0);
        async_ld16(gA1 + koff, lA1);
        async_ld16(gB0 + koff, lB0);
        async_ld16(gB1 + koff, lB1);
        __syncthreads();                         // DMA drained (vmcnt before barrier)
        bf16x8 af[4], bfr[4];
#pragma unroll
        for (int f = 0; f < 4; f++)
            af[f] = *(const bf16x8*)(Als + ((wr >> 4) + f) * 512 + q * 128 + l15 * 8);
#pragma unroll
        for (int f = 0; f < 4; f++)
            bfr[f] = *(const bf16x8*)(Bls + ((wc >> 4) + f) * 512 + q * 128 + l15 * 8);
#pragma unroll
        for (int fm = 0; fm < 4; fm++)
#pragma unroll
            for (int fn = 0; fn < 4; fn++)
                acc[fm][fn] = MFMA16x16(af[fm], bfr[fn], acc[fm][fn]);
    }
#pragma unroll
    for (int fm = 0; fm < 4; fm++) {
        const int rowb = m0 + wr + fm * 16 + q * 4;
#pragma unroll
        for (int fn = 0; fn < 4; fn++) {
            const int col = n0 + wc + fn * 16 + l15;
            float* dst = accbuf + (size_t)rowb * N_HP + col;
#pragma unroll
            for (int r = 0; r < 4; r++)
                atomicAdd(dst + (size_t)r * N_HP, acc[fm][fn][r]);
        }
    }
}

// ---------------- bias + tanh epilogue: accbuf f32 -> hbuf bf16
__global__ __launch_bounds__(256) void k_tanh(const float* __restrict__ accbuf, const float* __restrict__ b1,
                                              u16* __restrict__ hbuf) {
    const int i = blockIdx.x * 256 + threadIdx.x;
    const int col = i % N_HP;
    float e = accbuf[i] + (col < N_H ? b1[col] : 0.f);
    float ex = __expf(2.f * e);
    hbuf[i] = f2bf((ex - 1.f) / (ex + 1.f));
}

// ---------------- GEMM2: enc = h @ W2 + b2 ; z, zn, KL epilogue. 1 wave per 16 rows.
__global__ __launch_bounds__(64) void k_gemm2(const u16* __restrict__ hbuf, const u16* __restrict__ w2t,
                                              const float* __restrict__ b2, float* __restrict__ z_out,
                                              float* __restrict__ kl_out, u16* __restrict__ znb) {
    const int m0 = blockIdx.x * 16;
    const int lane = threadIdx.x;
    const int q = lane >> 4, l15 = lane & 15;
    f32x4 acc[25];
#pragma unroll
    for (int f = 0; f < 25; f++) acc[f] = (f32x4){0.f, 0.f, 0.f, 0.f};
    for (int s = 0; s < N_HP / 32; s++) {
        bf16x8 a = *(const bf16x8*)(hbuf + (size_t)(m0 + l15) * N_HP + s * 32 + q * 8);
#pragma unroll
        for (int f = 0; f < 25; f++) {
            bf16x8 bb = *(const bf16x8*)(w2t + (size_t)(f * 16 + l15) * N_HP + s * 32 + q * 8);
            acc[f] = MFMA16x16(a, bb, acc[f]);
        }
    }
    float sumsq[4] = {0.f, 0.f, 0.f, 0.f}, kls[4] = {0.f, 0.f, 0.f, 0.f};
#pragma unroll
    for (int f = 0; f < 25; f++) {
        const int n = f * 16 + l15;
        const float bias = b2[n];
#pragma unroll
        for (int r = 0; r < 4; r++) {
            float e = acc[f][r] + bias;
            if (n < N_LAT) {
                sumsq[r] += e * e;
                kls[r] += e * e;
                z_out[(size_t)(m0 + q * 4 + r) * N_LAT + n] = e;
            } else {
                kls[r] += __expf(e) - 1.f - e;
            }
        }
    }
#pragma unroll
    for (int r = 0; r < 4; r++)
#pragma unroll
        for (int m = 1; m < 16; m <<= 1) {
            sumsq[r] += __shfl_xor(sumsq[r], m);
            kls[r] += __shfl_xor(kls[r], m);
        }
    float inv[4];
#pragma unroll
    for (int r = 0; r < 4; r++) inv[r] = 1.f / fmaxf(sqrtf(sumsq[r]), EPSF);
#pragma unroll
    for (int f = 0; f < 25; f++) {
        const int n = f * 16 + l15;
        const float bias = b2[n];
#pragma unroll
        for (int r = 0; r < 4; r++) {
            const int row = m0 + q * 4 + r;
            float e = acc[f][r] + bias;
            if (n < N_LAT) znb[(size_t)row * N_DP + n] = f2bf(e * inv[r]);
            else if (n < N_DP) znb[(size_t)row * N_DP + n] = 0;
        }
    }
    if (l15 == 0) {
        float s = (kls[0] + kls[1] + kls[2] + kls[3]) * (0.5f / (float)N_ROWS);
        atomicAdd(kl_out, s);
    }
}

// ---------------- GEMM3 fused, 2 users/block: new_output[b][i] = log(mean_k exp(zn.itn*10) + 1)
__global__ __launch_bounds__(256) void k_outred(const u16* __restrict__ znb, const u16* __restrict__ itn,
                                                float* __restrict__ no_out) {
    __shared__ u16 zls[64 * N_DP];
    const int b0 = blockIdx.x * 2;
    const int t = threadIdx.x;
    for (int i = t; i < (64 * N_DP) / 8; i += 256)
        ((uint4*)zls)[i] = ((const uint4*)(znb + (size_t)b0 * 32 * N_DP))[i];
    __syncthreads();
    const int lane = t & 63, w = t >> 6;
    const int q = lane >> 4, l15 = lane & 15;
    bf16x8 af[4][7];
#pragma unroll
    for (int u2 = 0; u2 < 4; u2++)
#pragma unroll
        for (int s = 0; s < 7; s++)
            af[u2][s] = *(const bf16x8*)(zls + (u2 * 16 + l15) * N_DP + s * 32 + q * 8);
    for (int tt = blockIdx.y * 4 + w; tt < 750; tt += 128) {
        const int i0 = tt * 16;
        bf16x8 bfr[7];
#pragma unroll
        for (int s = 0; s < 7; s++)
            bfr[s] = *(const bf16x8*)(itn + (size_t)(i0 + l15) * N_DP + s * 32 + q * 8);
        f32x4 a[4];
#pragma unroll
        for (int u2 = 0; u2 < 4; u2++) a[u2] = (f32x4){0.f, 0.f, 0.f, 0.f};
#pragma unroll
        for (int s = 0; s < 7; s++)
#pragma unroll
            for (int u2 = 0; u2 < 4; u2++)
                a[u2] = MFMA16x16(af[u2][s], bfr[s], a[u2]);
        float se0 = 0.f, se1 = 0.f;
#pragma unroll
        for (int r = 0; r < 4; r++) {
            se0 += __expf(a[0][r] * 10.f) + __expf(a[1][r] * 10.f);
            se1 += __expf(a[2][r] * 10.f) + __expf(a[3][r] * 10.f);
        }
        se0 += __shfl_xor(se0, 16); se0 += __shfl_xor(se0, 32);
        se1 += __shfl_xor(se1, 16); se1 += __shfl_xor(se1, 32);
        if (lane < 16) {
            no_out[(size_t)b0 * N_I + i0 + lane] = __logf(se0 * (1.f / 32.f) + 1.f);
            no_out[(size_t)(b0 + 1) * N_I + i0 + lane] = __logf(se1 * (1.f / 32.f) + 1.f);
        }
    }
}

extern "C" void kernel_launch(void* const* d_in, const int* in_sizes, int n_in,
                              void* d_out, int out_size, void* d_ws, size_t ws_size,
                              hipStream_t stream) {
    const float* rating = (const float*)d_in[0];
    const int* idx = (const int*)d_in[1];
    const float* gram = (const float*)d_in[2];
    const float* W1 = (const float*)d_in[3];
    const float* b1 = (const float*)d_in[4];
    const float* W2 = (const float*)d_in[5];
    const float* b2 = (const float*)d_in[6];
    const float* items = (const float*)d_in[7];

    float* out = (float*)d_out;
    float* z_out = out;
    float* no_out = out + OFF_NO;
    float* kl_out = out + OFF_KL;
    float* x_out = out + OFF_X;

    // ws lifetime-aliased layout (total 124,149,760 B):
    //   [0, 98.3M)   xb (xnorm->gemm1), then reused: hbuf@0 | znb@5.24M | itn@7.08M | w2t@12.45M
    //   [98.3M, 113.7M) w1t
    //   [113.7M, 124.1M) accbuf f32
    char* ws = (char*)d_ws;
    u16* xb = (u16*)ws;
    u16* hbuf = (u16*)ws;
    u16* znb = (u16*)(ws + 5242880);
    u16* itn = (u16*)(ws + 7077888);
    u16* w2t = (u16*)(ws + 12453888);
    u16* w1t = (u16*)(ws + 98304000);
    float* accbuf = (float*)(ws + 113664000);

    hipMemsetAsync(kl_out, 0, 4, stream);
    hipMemsetAsync(accbuf, 0, (size_t)N_ROWS * N_HP * 4, stream);
    k_w1t<<<dim3(N_I / 32, N_HP / 32), dim3(32, 8), 0, stream>>>(W1, w1t);
    k_xnorm<<<N_ROWS, 256, 0, stream>>>(rating, idx, gram, x_out, xb);
    k_gemm1<<<dim3(N_ROWS / 128, N_HP / 128, SPLITK), 256, 0, stream>>>(xb, w1t, accbuf);
    k_tanh<<<(N_ROWS * N_HP) / 256, 256, 0, stream>>>(accbuf, b1, hbuf);
    k_w2t<<<dim3(N_HP / 32, 13), dim3(32, 8), 0, stream>>>(W2, w2t);
    k_itemn<<<N_I / 4, 256, 0, stream>>>(items, itn);
    k_gemm2<<<N_ROWS / 16, 64, 0, stream>>>(hbuf, w2t, b2, z_out, kl_out, znb);
    k_outred<<<dim3(N_B / 2, 32), 256, 0, stream>>>(znb, itn, no_out);
}